// Round 1
// baseline (113.103 us; speedup 1.0000x reference)
//
#include <hip/hip_runtime.h>

#define NB 8192
#define ANUM 5
#define OT_ELEMS (NB * 1024)   // 8388608 floats of Ot, then Mt
#define EPSF 1e-10f

// ---------------- Kernel 1: Cayley matrices M = (I-S)^-1 (I+S), stored transposed ----------------
__global__ void cayley_kernel(const float* __restrict__ Br,
                              const float* __restrict__ Bt,
                              const float* __restrict__ By,
                              float* __restrict__ MT_out) {
  __shared__ float A[32][33];
  __shared__ float R[32][33];
  const float* B = (blockIdx.x == 0) ? Br : (blockIdx.x == 1) ? Bt : By;
  const int t = threadIdx.x;
  const int i = t >> 5, j = t & 31;
  // skew: L[i][j] = (j<i) ? b[i-1+j] : 0 ; S = L - L^T   (idx never clips for used entries)
  float Lij = (j < i) ? B[i - 1 + j] : 0.0f;
  float Lji = (i < j) ? B[j - 1 + i] : 0.0f;
  float S = Lij - Lji;
  float eye = (i == j) ? 1.0f : 0.0f;
  A[i][j] = eye - S;   // I - S
  R[i][j] = eye + S;   // I + S
  __syncthreads();
  // Gauss-Jordan (no pivoting: I-S has positive-definite symmetric part)
  for (int p = 0; p < 32; ++p) {
    float f = A[i][p] / A[p][p];
    __syncthreads();
    if (i != p) {
      A[i][j] -= f * A[p][j];
      R[i][j] -= f * R[p][j];
    }
    __syncthreads();
  }
  // M[i][j] = R[i][j]/A[i][i]; store TRANSPOSED: MT[mat][j*32+i] = M[i][j]
  MT_out[blockIdx.x * 1024 + j * 32 + i] = R[i][j] / A[i][i];
}

// ---------------- 4x4-tile 32x32 matmul step: acc[r][c] += sum_k P[k*32+po+r]*Q[k*32+qo+c] ----------------
__device__ __forceinline__ void mm32(const float* P, const float* Q,
                                     int po, int qo, float acc[4][4]) {
#pragma unroll
  for (int k = 0; k < 32; ++k) {
    const float4 a = *(const float4*)(P + k * 32 + po);
    const float4 b = *(const float4*)(Q + k * 32 + qo);
    acc[0][0] = fmaf(a.x, b.x, acc[0][0]);
    acc[0][1] = fmaf(a.x, b.y, acc[0][1]);
    acc[0][2] = fmaf(a.x, b.z, acc[0][2]);
    acc[0][3] = fmaf(a.x, b.w, acc[0][3]);
    acc[1][0] = fmaf(a.y, b.x, acc[1][0]);
    acc[1][1] = fmaf(a.y, b.y, acc[1][1]);
    acc[1][2] = fmaf(a.y, b.z, acc[1][2]);
    acc[1][3] = fmaf(a.y, b.w, acc[1][3]);
    acc[2][0] = fmaf(a.z, b.x, acc[2][0]);
    acc[2][1] = fmaf(a.z, b.y, acc[2][1]);
    acc[2][2] = fmaf(a.z, b.z, acc[2][2]);
    acc[2][3] = fmaf(a.z, b.w, acc[2][3]);
    acc[3][0] = fmaf(a.w, b.x, acc[3][0]);
    acc[3][1] = fmaf(a.w, b.y, acc[3][1]);
    acc[3][2] = fmaf(a.w, b.z, acc[3][2]);
    acc[3][3] = fmaf(a.w, b.w, acc[3][3]);
  }
}

// ---------------- Kernel 2: main fused SPDSRU step. One wave (64 lanes) per batch. ----------------
__global__ __launch_bounds__(256) void spdsru_main(
    const float* __restrict__ X, const float* __restrict__ state,
    const float* __restrict__ WR, const float* __restrict__ Wt,
    const float* __restrict__ Wphi, const float* __restrict__ Ws,
    const float* __restrict__ MT, float* __restrict__ out) {
  __shared__ float sMT[3 * 1024];   // M_R^T, M_T^T, M_Y^T  (MT[k*32+i] = M[i][k])
  __shared__ float sA[4][1024];     // per-wave operand buffer (normal orientation)
  __shared__ float sB[4][1024];     // per-wave tmp buffer (transposed orientation)
  const int t = threadIdx.x;
  for (int idx = t; idx < 3 * 1024; idx += 256) sMT[idx] = MT[idx];

  // uniform scalar weights
  float wr[5], wsn[5];
  float sR = 0.f, sS = 0.f;
#pragma unroll
  for (int a = 0; a < 5; ++a) { float v = WR[a]; wr[a] = v * v; sR += v * v; }
#pragma unroll
  for (int a = 0; a < 5; ++a) { float v = Ws[a]; wsn[a] = v * v; sS += v * v; }
  const float invR = 1.0f / (sR + EPSF), invS = 1.0f / (sS + EPSF);
#pragma unroll
  for (int a = 0; a < 5; ++a) { wr[a] *= invR; wsn[a] *= invS; }
  const float wt2 = Wt[0] * Wt[0], wp2 = Wphi[0] * Wphi[0];
  const float at = wt2 / (wt2 + wp2 + EPSF);
  const float omat = 1.0f - at;

  const int wave = t >> 6, lane = t & 63;
  const int i0 = (lane >> 3) << 2;   // row group
  const int j0 = (lane & 7) << 2;    // col group
  const int batch = blockIdx.x * 4 + wave;
  float* Abuf = sA[wave];
  float* Bbuf = sB[wave];
  const float* MR = sMT;
  const float* MTt = sMT + 1024;
  const float* MY = sMT + 2048;

  // load state (kept in registers for the whole batch) and X
  const float* stp = state + (size_t)batch * (ANUM * 1024);
  const float* xp = X + (size_t)batch * 1024;
  float4 m[5][4];
#pragma unroll
  for (int a = 0; a < 5; ++a)
#pragma unroll
    for (int r = 0; r < 4; ++r)
      m[a][r] = *(const float4*)(stp + a * 1024 + (i0 + r) * 32 + j0);
  float4 x[4];
#pragma unroll
  for (int r = 0; r < 4; ++r) x[r] = *(const float4*)(xp + (i0 + r) * 32 + j0);

  // ---- Yt = sum_a wr[a] * Mt_1[a]  -> Abuf ----
#pragma unroll
  for (int r = 0; r < 4; ++r) {
    float4 y;
    y.x = wr[0]*m[0][r].x + wr[1]*m[1][r].x + wr[2]*m[2][r].x + wr[3]*m[3][r].x + wr[4]*m[4][r].x;
    y.y = wr[0]*m[0][r].y + wr[1]*m[1][r].y + wr[2]*m[2][r].y + wr[3]*m[3][r].y + wr[4]*m[4][r].y;
    y.z = wr[0]*m[0][r].z + wr[1]*m[1][r].z + wr[2]*m[2][r].z + wr[3]*m[3][r].z + wr[4]*m[4][r].z;
    y.w = wr[0]*m[0][r].w + wr[1]*m[1][r].w + wr[2]*m[2][r].w + wr[3]*m[3][r].w + wr[4]*m[4][r].w;
    *(float4*)(Abuf + (i0 + r) * 32 + j0) = y;
  }
  __syncthreads();   // (1) Yt visible (also covers sMT staging)

  // ---- tmp1 = M_R * Yt  (stored transposed into Bbuf) ----
  float t1[4][4] = {};
  mm32(MR, Abuf, i0, j0, t1);
#pragma unroll
  for (int c = 0; c < 4; ++c)
    *(float4*)(Bbuf + (j0 + c) * 32 + i0) = make_float4(t1[0][c], t1[1][c], t1[2][c], t1[3][c]);
  __syncthreads();   // (2)

  // ---- Rt = tmp1 * M_R^T ; Tt = (1-at)X + at*Rt -> Abuf ----
  float t2[4][4] = {};
  mm32(Bbuf, MR, i0, j0, t2);
#pragma unroll
  for (int r = 0; r < 4; ++r) {
    float4 v;
    v.x = omat * x[r].x + at * t2[r][0];
    v.y = omat * x[r].y + at * t2[r][1];
    v.z = omat * x[r].z + at * t2[r][2];
    v.w = omat * x[r].w + at * t2[r][3];
    *(float4*)(Abuf + (i0 + r) * 32 + j0) = v;
  }
  __syncthreads();   // (3)

  // ---- tmp2 = M_T * Tt (transposed into Bbuf) ----
  float u1[4][4] = {};
  mm32(MTt, Abuf, i0, j0, u1);
#pragma unroll
  for (int c = 0; c < 4; ++c)
    *(float4*)(Bbuf + (j0 + c) * 32 + i0) = make_float4(u1[0][c], u1[1][c], u1[2][c], u1[3][c]);
  __syncthreads();   // (4)

  // ---- Phit = tmp2 * M_T^T ----
  float u2[4][4] = {};
  mm32(Bbuf, MTt, i0, j0, u2);

  // ---- Mt[a] = (1-alpha)Mt_1[a] + alpha*Phit  (write out) ; St = sum_a wsn[a]*Mt[a] -> Abuf ----
  float* outMt = out + OT_ELEMS + (size_t)batch * (ANUM * 1024);
  float4 stl[4];
#pragma unroll
  for (int r = 0; r < 4; ++r) stl[r] = make_float4(0.f, 0.f, 0.f, 0.f);
  const float alpha[5] = {0.01f, 0.25f, 0.5f, 0.9f, 0.99f};
#pragma unroll
  for (int a = 0; a < 5; ++a) {
    const float al = alpha[a], om = 1.0f - al;
#pragma unroll
    for (int r = 0; r < 4; ++r) {
      float4 v;
      v.x = om * m[a][r].x + al * u2[r][0];
      v.y = om * m[a][r].y + al * u2[r][1];
      v.z = om * m[a][r].z + al * u2[r][2];
      v.w = om * m[a][r].w + al * u2[r][3];
      *(float4*)(outMt + a * 1024 + (i0 + r) * 32 + j0) = v;
      stl[r].x = fmaf(wsn[a], v.x, stl[r].x);
      stl[r].y = fmaf(wsn[a], v.y, stl[r].y);
      stl[r].z = fmaf(wsn[a], v.z, stl[r].z);
      stl[r].w = fmaf(wsn[a], v.w, stl[r].w);
    }
  }
#pragma unroll
  for (int r = 0; r < 4; ++r)
    *(float4*)(Abuf + (i0 + r) * 32 + j0) = stl[r];
  __syncthreads();   // (5)

  // ---- tmp3 = M_Y * St (transposed into Bbuf) ----
  float v1[4][4] = {};
  mm32(MY, Abuf, i0, j0, v1);
#pragma unroll
  for (int c = 0; c < 4; ++c)
    *(float4*)(Bbuf + (j0 + c) * 32 + i0) = make_float4(v1[0][c], v1[1][c], v1[2][c], v1[3][c]);
  __syncthreads();   // (6)

  // ---- Ot = tmp3 * M_Y^T ----
  float v2[4][4] = {};
  mm32(Bbuf, MY, i0, j0, v2);
  float* outOt = out + (size_t)batch * 1024;
#pragma unroll
  for (int r = 0; r < 4; ++r)
    *(float4*)(outOt + (i0 + r) * 32 + j0) = make_float4(v2[r][0], v2[r][1], v2[r][2], v2[r][3]);
}

extern "C" void kernel_launch(void* const* d_in, const int* in_sizes, int n_in,
                              void* d_out, int out_size, void* d_ws, size_t ws_size,
                              hipStream_t stream) {
  const float* X     = (const float*)d_in[0];
  const float* state = (const float*)d_in[1];
  const float* WR    = (const float*)d_in[2];
  const float* Wt    = (const float*)d_in[3];
  const float* Wphi  = (const float*)d_in[4];
  const float* Ws    = (const float*)d_in[5];
  const float* Br    = (const float*)d_in[6];
  const float* Bt    = (const float*)d_in[7];
  const float* By    = (const float*)d_in[8];
  float* mt_ws = (float*)d_ws;   // 3*1024 floats: M_R^T, M_T^T, M_Y^T
  float* outp = (float*)d_out;

  cayley_kernel<<<3, 1024, 0, stream>>>(Br, Bt, By, mt_ws);
  spdsru_main<<<NB / 4, 256, 0, stream>>>(X, state, WR, Wt, Wphi, Ws, mt_ws, outp);
}

// Round 2
// 108.123 us; speedup vs baseline: 1.0461x; 1.0461x over previous
//
#include <hip/hip_runtime.h>

#define NB 8192
#define ANUM 5
#define OT_ELEMS (NB * 1024)   // 8388608 floats of Ot, then Mt
#define EPSF 1e-10f

// Wave-local ordering fence: DS ops from one wave execute in order; this only
// stops the COMPILER from reordering LDS ops across phase boundaries and makes
// the write->read boundary explicit.
#define WAVE_FENCE() asm volatile("s_waitcnt lgkmcnt(0)" ::: "memory")

// ---------------- Kernel 1: Cayley matrices M = (I-S)^-1 (I+S), stored transposed ----------------
__global__ void cayley_kernel(const float* __restrict__ Br,
                              const float* __restrict__ Bt,
                              const float* __restrict__ By,
                              float* __restrict__ MT_out) {
  __shared__ float A[32][33];
  __shared__ float R[32][33];
  const float* B = (blockIdx.x == 0) ? Br : (blockIdx.x == 1) ? Bt : By;
  const int t = threadIdx.x;
  const int i = t >> 5, j = t & 31;
  float Lij = (j < i) ? B[i - 1 + j] : 0.0f;
  float Lji = (i < j) ? B[j - 1 + i] : 0.0f;
  float S = Lij - Lji;
  float eye = (i == j) ? 1.0f : 0.0f;
  A[i][j] = eye - S;   // I - S
  R[i][j] = eye + S;   // I + S
  __syncthreads();
  for (int p = 0; p < 32; ++p) {
    float f = A[i][p] / A[p][p];
    __syncthreads();
    if (i != p) {
      A[i][j] -= f * A[p][j];
      R[i][j] -= f * R[p][j];
    }
    __syncthreads();
  }
  // store TRANSPOSED: MT[mat][j*32+i] = M[i][j]  (row-major sMT holds M^T)
  MT_out[blockIdx.x * 1024 + j * 32 + i] = R[i][j] / A[i][i];
}

// ---- mm_MQ: acc[r][c] += sum_k M[k][i0+r] * buf[k][j0+c]   (M unswizzled/broadcast, buf swizzled)
__device__ __forceinline__ void mm_MQ(const float* __restrict__ M, const float* __restrict__ buf,
                                      int i0, int j0, float acc[4][4]) {
#pragma unroll
  for (int k = 0; k < 32; ++k) {
    const float4 a = *(const float4*)(M + k * 32 + i0);
    const float4 b = *(const float4*)(buf + k * 32 + (j0 ^ (k & 28)));
    acc[0][0] = fmaf(a.x, b.x, acc[0][0]);
    acc[0][1] = fmaf(a.x, b.y, acc[0][1]);
    acc[0][2] = fmaf(a.x, b.z, acc[0][2]);
    acc[0][3] = fmaf(a.x, b.w, acc[0][3]);
    acc[1][0] = fmaf(a.y, b.x, acc[1][0]);
    acc[1][1] = fmaf(a.y, b.y, acc[1][1]);
    acc[1][2] = fmaf(a.y, b.z, acc[1][2]);
    acc[1][3] = fmaf(a.y, b.w, acc[1][3]);
    acc[2][0] = fmaf(a.z, b.x, acc[2][0]);
    acc[2][1] = fmaf(a.z, b.y, acc[2][1]);
    acc[2][2] = fmaf(a.z, b.z, acc[2][2]);
    acc[2][3] = fmaf(a.z, b.w, acc[2][3]);
    acc[3][0] = fmaf(a.w, b.x, acc[3][0]);
    acc[3][1] = fmaf(a.w, b.y, acc[3][1]);
    acc[3][2] = fmaf(a.w, b.z, acc[3][2]);
    acc[3][3] = fmaf(a.w, b.w, acc[3][3]);
  }
}

// ---- mm_PM: acc[r][c] += sum_k buf[k][i0+r] * M[k][j0+c]   (buf swizzled, M broadcast)
__device__ __forceinline__ void mm_PM(const float* __restrict__ buf, const float* __restrict__ M,
                                      int i0, int j0, float acc[4][4]) {
#pragma unroll
  for (int k = 0; k < 32; ++k) {
    const float4 a = *(const float4*)(buf + k * 32 + (i0 ^ (k & 28)));
    const float4 b = *(const float4*)(M + k * 32 + j0);
    acc[0][0] = fmaf(a.x, b.x, acc[0][0]);
    acc[0][1] = fmaf(a.x, b.y, acc[0][1]);
    acc[0][2] = fmaf(a.x, b.z, acc[0][2]);
    acc[0][3] = fmaf(a.x, b.w, acc[0][3]);
    acc[1][0] = fmaf(a.y, b.x, acc[1][0]);
    acc[1][1] = fmaf(a.y, b.y, acc[1][1]);
    acc[1][2] = fmaf(a.y, b.z, acc[1][2]);
    acc[1][3] = fmaf(a.y, b.w, acc[1][3]);
    acc[2][0] = fmaf(a.z, b.x, acc[2][0]);
    acc[2][1] = fmaf(a.z, b.y, acc[2][1]);
    acc[2][2] = fmaf(a.z, b.z, acc[2][2]);
    acc[2][3] = fmaf(a.z, b.w, acc[2][3]);
    acc[3][0] = fmaf(a.w, b.x, acc[3][0]);
    acc[3][1] = fmaf(a.w, b.y, acc[3][1]);
    acc[3][2] = fmaf(a.w, b.z, acc[3][2]);
    acc[3][3] = fmaf(a.w, b.w, acc[3][3]);
  }
}

// ---------------- Kernel 2: main fused SPDSRU step. One wave (64 lanes) per batch. ----------------
// Single wave-private LDS buffer (ping-ponged in place; safe: per-wave DS ops are in-order),
// XOR-swizzled (col ^= row&28) so strided float4 writes hit all 32 banks.
// LDS/block = 12KB (sMT) + 16KB (buf) = 28KB -> 5 blocks/CU; VGPR ~100 -> 20 waves/CU.
__global__ __launch_bounds__(256) void spdsru_main(
    const float* __restrict__ X, const float* __restrict__ state,
    const float* __restrict__ WR, const float* __restrict__ Wt,
    const float* __restrict__ Wphi, const float* __restrict__ Ws,
    const float* __restrict__ MT, float* __restrict__ out) {
  __shared__ float sMT[3 * 1024];   // M_R^T, M_T^T, M_Y^T (row-major = M^T)
  __shared__ float sBuf[4][1024];   // per-wave operand/tmp buffer (swizzled)
  const int t = threadIdx.x;
  for (int idx = t; idx < 768; idx += 256)
    ((float4*)sMT)[idx] = ((const float4*)MT)[idx];

  // uniform scalar weights
  float wr[5], wsn[5];
  float sR = 0.f, sS = 0.f;
#pragma unroll
  for (int a = 0; a < 5; ++a) { float v = WR[a]; wr[a] = v * v; sR += v * v; }
#pragma unroll
  for (int a = 0; a < 5; ++a) { float v = Ws[a]; wsn[a] = v * v; sS += v * v; }
  const float invR = 1.0f / (sR + EPSF), invS = 1.0f / (sS + EPSF);
#pragma unroll
  for (int a = 0; a < 5; ++a) { wr[a] *= invR; wsn[a] *= invS; }
  const float wt2 = Wt[0] * Wt[0], wp2 = Wphi[0] * Wphi[0];
  const float at = wt2 / (wt2 + wp2 + EPSF);
  const float omat = 1.0f - at;

  const int wave = t >> 6, lane = t & 63;
  const int i0 = (lane >> 3) << 2;   // row group (0,4,...,28)
  const int j0 = (lane & 7) << 2;    // col group (0,4,...,28)
  const int batch = blockIdx.x * 4 + wave;
  float* buf = sBuf[wave];
  const float* MR  = sMT;
  const float* MTt = sMT + 1024;
  const float* MY  = sMT + 2048;

  // load state (kept in registers for the whole batch) and X
  const float* stp = state + (size_t)batch * (ANUM * 1024);
  const float* xp = X + (size_t)batch * 1024;
  float4 m[5][4];
#pragma unroll
  for (int a = 0; a < 5; ++a)
#pragma unroll
    for (int r = 0; r < 4; ++r)
      m[a][r] = *(const float4*)(stp + a * 1024 + (i0 + r) * 32 + j0);
  float4 x[4];
#pragma unroll
  for (int r = 0; r < 4; ++r) x[r] = *(const float4*)(xp + (i0 + r) * 32 + j0);

  __syncthreads();   // the ONLY block barrier: sMT staging visible to all waves

  // ---- Yt = sum_a wr[a]*Mt_1[a]  -> buf (normal orientation, swizzled) ----
#pragma unroll
  for (int r = 0; r < 4; ++r) {
    float4 y;
    y.x = wr[0]*m[0][r].x + wr[1]*m[1][r].x + wr[2]*m[2][r].x + wr[3]*m[3][r].x + wr[4]*m[4][r].x;
    y.y = wr[0]*m[0][r].y + wr[1]*m[1][r].y + wr[2]*m[2][r].y + wr[3]*m[3][r].y + wr[4]*m[4][r].y;
    y.z = wr[0]*m[0][r].z + wr[1]*m[1][r].z + wr[2]*m[2][r].z + wr[3]*m[3][r].z + wr[4]*m[4][r].z;
    y.w = wr[0]*m[0][r].w + wr[1]*m[1][r].w + wr[2]*m[2][r].w + wr[3]*m[3][r].w + wr[4]*m[4][r].w;
    *(float4*)(buf + (i0 + r) * 32 + (j0 ^ i0)) = y;
  }
  WAVE_FENCE();

  // ---- t1 = M_R * Yt ----
  float t1[4][4] = {};
  mm_MQ(MR, buf, i0, j0, t1);
  WAVE_FENCE();
#pragma unroll
  for (int c = 0; c < 4; ++c)
    *(float4*)(buf + (j0 + c) * 32 + (i0 ^ j0)) = make_float4(t1[0][c], t1[1][c], t1[2][c], t1[3][c]);
  WAVE_FENCE();

  // ---- Rt = t1 * M_R^T ; Tt = (1-at)X + at*Rt -> buf ----
  float t2[4][4] = {};
  mm_PM(buf, MR, i0, j0, t2);
  WAVE_FENCE();
#pragma unroll
  for (int r = 0; r < 4; ++r) {
    float4 v;
    v.x = omat * x[r].x + at * t2[r][0];
    v.y = omat * x[r].y + at * t2[r][1];
    v.z = omat * x[r].z + at * t2[r][2];
    v.w = omat * x[r].w + at * t2[r][3];
    *(float4*)(buf + (i0 + r) * 32 + (j0 ^ i0)) = v;
  }
  WAVE_FENCE();

  // ---- u1 = M_T * Tt ----
  float u1[4][4] = {};
  mm_MQ(MTt, buf, i0, j0, u1);
  WAVE_FENCE();
#pragma unroll
  for (int c = 0; c < 4; ++c)
    *(float4*)(buf + (j0 + c) * 32 + (i0 ^ j0)) = make_float4(u1[0][c], u1[1][c], u1[2][c], u1[3][c]);
  WAVE_FENCE();

  // ---- Phit = u1 * M_T^T ----
  float u2[4][4] = {};
  mm_PM(buf, MTt, i0, j0, u2);
  WAVE_FENCE();

  // ---- Mt[a] = (1-alpha)Mt_1[a] + alpha*Phit (write out); St = sum wsn[a]*Mt[a] -> buf ----
  float* outMt = out + OT_ELEMS + (size_t)batch * (ANUM * 1024);
  float4 stl[4];
#pragma unroll
  for (int r = 0; r < 4; ++r) stl[r] = make_float4(0.f, 0.f, 0.f, 0.f);
  const float alpha[5] = {0.01f, 0.25f, 0.5f, 0.9f, 0.99f};
#pragma unroll
  for (int a = 0; a < 5; ++a) {
    const float al = alpha[a], om = 1.0f - al;
#pragma unroll
    for (int r = 0; r < 4; ++r) {
      float4 v;
      v.x = om * m[a][r].x + al * u2[r][0];
      v.y = om * m[a][r].y + al * u2[r][1];
      v.z = om * m[a][r].z + al * u2[r][2];
      v.w = om * m[a][r].w + al * u2[r][3];
      *(float4*)(outMt + a * 1024 + (i0 + r) * 32 + j0) = v;
      stl[r].x = fmaf(wsn[a], v.x, stl[r].x);
      stl[r].y = fmaf(wsn[a], v.y, stl[r].y);
      stl[r].z = fmaf(wsn[a], v.z, stl[r].z);
      stl[r].w = fmaf(wsn[a], v.w, stl[r].w);
    }
  }
#pragma unroll
  for (int r = 0; r < 4; ++r)
    *(float4*)(buf + (i0 + r) * 32 + (j0 ^ i0)) = stl[r];
  WAVE_FENCE();

  // ---- v1 = M_Y * St ----
  float v1[4][4] = {};
  mm_MQ(MY, buf, i0, j0, v1);
  WAVE_FENCE();
#pragma unroll
  for (int c = 0; c < 4; ++c)
    *(float4*)(buf + (j0 + c) * 32 + (i0 ^ j0)) = make_float4(v1[0][c], v1[1][c], v1[2][c], v1[3][c]);
  WAVE_FENCE();

  // ---- Ot = v1 * M_Y^T ----
  float v2[4][4] = {};
  mm_PM(buf, MY, i0, j0, v2);
  float* outOt = out + (size_t)batch * 1024;
#pragma unroll
  for (int r = 0; r < 4; ++r)
    *(float4*)(outOt + (i0 + r) * 32 + j0) = make_float4(v2[r][0], v2[r][1], v2[r][2], v2[r][3]);
}

extern "C" void kernel_launch(void* const* d_in, const int* in_sizes, int n_in,
                              void* d_out, int out_size, void* d_ws, size_t ws_size,
                              hipStream_t stream) {
  const float* X     = (const float*)d_in[0];
  const float* state = (const float*)d_in[1];
  const float* WR    = (const float*)d_in[2];
  const float* Wt    = (const float*)d_in[3];
  const float* Wphi  = (const float*)d_in[4];
  const float* Ws    = (const float*)d_in[5];
  const float* Br    = (const float*)d_in[6];
  const float* Bt    = (const float*)d_in[7];
  const float* By    = (const float*)d_in[8];
  float* mt_ws = (float*)d_ws;   // 3*1024 floats: M_R^T, M_T^T, M_Y^T
  float* outp = (float*)d_out;

  cayley_kernel<<<3, 1024, 0, stream>>>(Br, Bt, By, mt_ws);
  spdsru_main<<<NB / 4, 256, 0, stream>>>(X, state, WR, Wt, Wphi, Ws, mt_ws, outp);
}